// Round 10
// baseline (1035.710 us; speedup 1.0000x reference)
//
#include <hip/hip_runtime.h>
#include <hip/hip_bf16.h>

#define NND 50000
#define NED 800000
#define NGR 64
#define EPSV 1e-5f
#define NSTR (NND + 8)   // padded column stride for nfT (4-elem zero guards)

// ---------------- CSR build: histogram / 3-phase scan / fill ----------------
__global__ void hist_kernel(const int* __restrict__ dst, int* __restrict__ cnt)
{
    int e = blockIdx.x * 256 + threadIdx.x;
    if (e < NED) atomicAdd(&cnt[dst[e]], 1);
}

__global__ void scanA_kernel(const int* __restrict__ cnt, int* __restrict__ bsum)
{
    __shared__ int buf[256];
    int t = threadIdx.x, base = blockIdx.x * 1024;
    int s = 0;
    for (int i = t; i < 1024; i += 256) {
        int idx = base + i;
        s += (idx < NND) ? cnt[idx] : 0;
    }
    buf[t] = s; __syncthreads();
    for (int off = 128; off; off >>= 1) {
        if (t < off) buf[t] += buf[t + off];
        __syncthreads();
    }
    if (t == 0) bsum[blockIdx.x] = buf[0];
}

__global__ void scanB_kernel(int* __restrict__ bsum, int* __restrict__ rowptr, int nb)
{
    if (threadIdx.x == 0) {
        int acc = 0;
        for (int i = 0; i < nb; i++) { int v = bsum[i]; bsum[i] = acc; acc += v; }
        rowptr[NND] = acc;
    }
}

__global__ void scanC_kernel(const int* __restrict__ cnt, const int* __restrict__ bsum,
                             int* __restrict__ rowptr, int* __restrict__ cursor)
{
    __shared__ int buf[1024];
    int t = threadIdx.x, idx = blockIdx.x * 1024 + t;
    int v = (idx < NND) ? cnt[idx] : 0;
    buf[t] = v; __syncthreads();
    for (int off = 1; off < 1024; off <<= 1) {
        int x = (t >= off) ? buf[t - off] : 0;
        __syncthreads();
        buf[t] += x;
        __syncthreads();
    }
    if (idx < NND) {
        int excl = buf[t] - v + bsum[blockIdx.x];
        rowptr[idx] = excl; cursor[idx] = excl;
    }
}

__global__ void fill_kernel(const int* __restrict__ src, const int* __restrict__ dst,
                            const float* __restrict__ ew, int* __restrict__ cursor,
                            int* __restrict__ csrs, float* __restrict__ csrw)
{
    int e = blockIdx.x * 256 + threadIdx.x;
    if (e < NED) {
        int pos = atomicAdd(&cursor[dst[e]], 1);
        csrs[pos] = src[e];
        csrw[pos] = ew[e];
    }
}

// ---------------- graph ranges via binary search on sorted graph_ids ----------------
__global__ void grstart_kernel(const int* __restrict__ gid, int* __restrict__ gr)
{
    int t = threadIdx.x;
    if (t > NGR) return;
    if (t == NGR) { gr[NGR] = NND; return; }
    int lo = 0, hi = NND;
    while (lo < hi) { int mid = (lo + hi) >> 1; if (gid[mid] < t) lo = mid + 1; else hi = mid; }
    gr[t] = lo;
}

// ---------------- K0: transpose node_feats [p][c] -> nfT [c][4+p] (padded) ---------
__global__ void transpose_kernel(const float* __restrict__ nf, float* __restrict__ nfT)
{
    __shared__ float tile[32][33];
    int tx = threadIdx.x & 31, ty = threadIdx.x >> 5;   // 32 x 8
    int p0 = blockIdx.x * 32, c0 = blockIdx.y * 32;
#pragma unroll
    for (int i = 0; i < 4; i++) {
        int p = p0 + ty + i * 8;
        if (p < NND) tile[ty + i * 8][tx] = nf[(size_t)p * 128 + c0 + tx];
    }
    __syncthreads();
#pragma unroll
    for (int i = 0; i < 4; i++) {
        int c = c0 + ty + i * 8;
        int p = p0 + tx;
        if (p < NND) nfT[(size_t)c * NSTR + 4 + p] = tile[tx][ty + i * 8];
    }
}

// zero the 4-elem guard bands of each padded column
__global__ void pad_kernel(float* __restrict__ nfT)
{
    int t = threadIdx.x;           // 1024 = 128 ch x 8 pad slots
    int c = t >> 3, i = t & 7;
    size_t off = (size_t)c * NSTR + (i < 4 ? i : (NND + i));  // 0..3 and NND+4..NND+7
    nfT[off] = 0.f;
}

// ---------------- fused conv + cross-connect(relu) + BN1 stats ----------------
// Block: (og of 8 out-ch, chunk of 1024 nodes). Computes all 3 branches so the
// relu-cross-connect Y[br]=relu(X[br])+X[br+1] is formed in-register (no X buffer).
template <int D>
__device__ __forceinline__ void conv_tap(const float4& lo, const float4& mi, const float4& hi,
                                         const float* __restrict__ wl, int c,
                                         float (&acc)[8][4])
{
    float f0[4], f1[4], f2[4];
    f1[0] = mi.x; f1[1] = mi.y; f1[2] = mi.z; f1[3] = mi.w;
    if (D == 1) {
        f0[0] = lo.w; f0[1] = mi.x; f0[2] = mi.y; f0[3] = mi.z;
        f2[0] = mi.y; f2[1] = mi.z; f2[2] = mi.w; f2[3] = hi.x;
    } else if (D == 2) {
        f0[0] = lo.z; f0[1] = lo.w; f0[2] = mi.x; f0[3] = mi.y;
        f2[0] = mi.z; f2[1] = mi.w; f2[2] = hi.x; f2[3] = hi.y;
    } else {
        f0[0] = lo.y; f0[1] = lo.z; f0[2] = lo.w; f0[3] = mi.x;
        f2[0] = mi.w; f2[1] = hi.x; f2[2] = hi.y; f2[3] = hi.z;
    }
    const int BR = D - 1;
    const float4* w0 = (const float4*)&wl[((BR * 3 + 0) * 128 + c) * 8];
    const float4* w1 = (const float4*)&wl[((BR * 3 + 1) * 128 + c) * 8];
    const float4* w2 = (const float4*)&wl[((BR * 3 + 2) * 128 + c) * 8];
#pragma unroll
    for (int jh = 0; jh < 2; jh++) {
        float4 a0 = w0[jh], a1 = w1[jh], a2 = w2[jh];
#pragma unroll
        for (int i = 0; i < 4; i++) {
            acc[jh * 4 + 0][i] += f0[i] * a0.x + f1[i] * a1.x + f2[i] * a2.x;
            acc[jh * 4 + 1][i] += f0[i] * a0.y + f1[i] * a1.y + f2[i] * a2.y;
            acc[jh * 4 + 2][i] += f0[i] * a0.z + f1[i] * a1.z + f2[i] * a2.z;
            acc[jh * 4 + 3][i] += f0[i] * a0.w + f1[i] * a1.w + f2[i] * a2.w;
        }
    }
}

__global__ __launch_bounds__(256)
void conv_y_stats_kernel(const float* __restrict__ nfT, const float* __restrict__ cw,
                         const float* __restrict__ cb, float* __restrict__ Y,
                         float* __restrict__ st1)
{
    __shared__ __align__(16) float wl[3 * 3 * 128 * 8];   // [br][k][c][j] : 36 KB
    const int t  = threadIdx.x;
    const int og = blockIdx.x;   // 0..11 (8 out channels)
    for (int l = t; l < 3 * 3 * 128 * 8; l += 256) {
        int j = l & 7; int c = (l >> 3) & 127; int kb = l >> 10;  // kb = br*3+k
        int k = kb % 3, br = kb / 3;
        wl[l] = cw[(((size_t)br * 96 + og * 8 + j) * 128 + c) * 3 + k];
    }
    __syncthreads();
    const int pq = blockIdx.y * 1024 + t * 4;
    float acc[3][8][4];
#pragma unroll
    for (int br = 0; br < 3; br++) {
#pragma unroll
        for (int j = 0; j < 8; j++) {
            float b = cb[br * 96 + og * 8 + j];
#pragma unroll
            for (int i = 0; i < 4; i++) acc[br][j][i] = b;
        }
    }
    for (int c = 0; c < 128; c++) {
        const float* col = nfT + (size_t)c * NSTR + 4;
        float4 lo = *(const float4*)(col + pq - 4);
        float4 mi = *(const float4*)(col + pq);
        float4 hi = *(const float4*)(col + pq + 4);
        conv_tap<1>(lo, mi, hi, wl, c, acc[0]);
        conv_tap<2>(lo, mi, hi, wl, c, acc[1]);
        conv_tap<3>(lo, mi, hi, wl, c, acc[2]);
    }
    // cross-connect in-register: y[br] = relu(x[br]) + x[(br+1)%3]
#pragma unroll
    for (int j = 0; j < 8; j++)
#pragma unroll
        for (int i = 0; i < 4; i++) {
            float a0 = acc[0][j][i], a1 = acc[1][j][i], a2 = acc[2][j][i];
            acc[0][j][i] = (a0 > 0.f ? a0 : 0.f) + a1;
            acc[1][j][i] = (a1 > 0.f ? a1 : 0.f) + a2;
            acc[2][j][i] = (a2 > 0.f ? a2 : 0.f) + a0;
        }
    bool val[4];
#pragma unroll
    for (int i = 0; i < 4; i++) val[i] = (pq + i) < NND;
    // BN1 stats: shuffle-reduce per (br, j), lane0 atomics (24 x 2 per wave)
    const size_t NM = (size_t)NND * 96;
#pragma unroll
    for (int br = 0; br < 3; br++)
#pragma unroll
        for (int j = 0; j < 8; j++) {
            float s = 0.f, q = 0.f;
#pragma unroll
            for (int i = 0; i < 4; i++)
                if (val[i]) { float v = acc[br][j][i]; s += v; q += v * v; }
            for (int off = 32; off; off >>= 1) {
                s += __shfl_down(s, off, 64);
                q += __shfl_down(q, off, 64);
            }
            if ((t & 63) == 0) {
                unsafeAtomicAdd(&st1[br * 96 + og * 8 + j], s);
                unsafeAtomicAdd(&st1[288 + br * 96 + og * 8 + j], q);
            }
        }
    // write Y
#pragma unroll
    for (int br = 0; br < 3; br++)
#pragma unroll
        for (int i = 0; i < 4; i++) {
            if (!val[i]) continue;
            float* yo = Y + (size_t)br * NM + (size_t)(pq + i) * 96 + og * 8;
            float4 v0, v1;
            v0.x = acc[br][0][i]; v0.y = acc[br][1][i]; v0.z = acc[br][2][i]; v0.w = acc[br][3][i];
            v1.x = acc[br][4][i]; v1.y = acc[br][5][i]; v1.z = acc[br][6][i]; v1.w = acc[br][7][i];
            ((float4*)yo)[0] = v0;
            ((float4*)yo)[1] = v1;
        }
}

// ---------------- BN finalize ----------------
__global__ void bn_finalize_kernel(const float* __restrict__ st, const float* __restrict__ g,
                                   const float* __restrict__ b,
                                   float* __restrict__ sc, float* __restrict__ sh,
                                   int C, int gmod)
{
    int t = threadIdx.x;
    if (t >= C) return;
    float mean = st[t] / (float)NND;
    float var  = st[C + t] / (float)NND - mean * mean;
    float rs = rsqrtf(var + EPSV);
    float gg = g[t % gmod], bb = b[t % gmod];
    float s = gg * rs;
    sc[t] = s; sh[t] = bb - mean * s;
}

// ---------------- K4: pull GCN aggregate, 3 branches fused, float4 channels ------
__global__ void pull_bn_kernel(const float* __restrict__ Y, const int* __restrict__ rowptr,
                               const int* __restrict__ csrs, const float* __restrict__ csrw,
                               const float* __restrict__ sc1, const float* __restrict__ sh1,
                               float* __restrict__ AGG)
{
    int id = blockIdx.x * 256 + threadIdx.x;
    if (id >= NND * 24) return;
    int p = id / 24, q = id % 24;
    const float4* Y4 = (const float4*)Y;
    const size_t NQ = (size_t)NND * 24;
    int beg = rowptr[p], end = rowptr[p + 1];
    float a0x=0,a0y=0,a0z=0,a0w=0, a1x=0,a1y=0,a1z=0,a1w=0, a2x=0,a2y=0,a2z=0,a2w=0;
    float wsum = 0.f;
    for (int i = beg; i < end; i++) {
        float w = csrw[i];
        size_t off = (size_t)csrs[i] * 24 + q;
        float4 v0 = Y4[off];
        float4 v1 = Y4[NQ + off];
        float4 v2 = Y4[2 * NQ + off];
        a0x += w * v0.x; a0y += w * v0.y; a0z += w * v0.z; a0w += w * v0.w;
        a1x += w * v1.x; a1y += w * v1.y; a1z += w * v1.z; a1w += w * v1.w;
        a2x += w * v2.x; a2y += w * v2.y; a2z += w * v2.z; a2w += w * v2.w;
        wsum += w;
    }
    const float4* S4 = (const float4*)sc1;
    const float4* H4 = (const float4*)sh1;
    float4* AG4 = (float4*)AGG;
    size_t ob = (size_t)p * 24 + q;
    {
        float4 s = S4[q], h = H4[q], r;
        r.x = s.x * a0x + h.x * wsum; r.y = s.y * a0y + h.y * wsum;
        r.z = s.z * a0z + h.z * wsum; r.w = s.w * a0w + h.w * wsum;
        AG4[ob] = r;
    }
    {
        float4 s = S4[24 + q], h = H4[24 + q], r;
        r.x = s.x * a1x + h.x * wsum; r.y = s.y * a1y + h.y * wsum;
        r.z = s.z * a1z + h.z * wsum; r.w = s.w * a1w + h.w * wsum;
        AG4[NQ + ob] = r;
    }
    {
        float4 s = S4[48 + q], h = H4[48 + q], r;
        r.x = s.x * a2x + h.x * wsum; r.y = s.y * a2y + h.y * wsum;
        r.z = s.z * a2z + h.z * wsum; r.w = s.w * a2w + h.w * wsum;
        AG4[2 * NQ + ob] = r;
    }
}

// ---------------- pull gather, float2-vectorized (C even) ----------------
template <int C>
__global__ void pull2_kernel(const float* __restrict__ in, const int* __restrict__ rowptr,
                             const int* __restrict__ csrs, const float* __restrict__ csrw,
                             float* __restrict__ out)
{
    constexpr int C2 = C / 2;
    int id = blockIdx.x * 256 + threadIdx.x;
    if (id >= NND * C2) return;
    int p = id / C2, q = id % C2;
    const float2* in2 = (const float2*)in;
    int beg = rowptr[p], end = rowptr[p + 1];
    float ax = 0.f, ay = 0.f;
    for (int i = beg; i < end; i++) {
        float w = csrw[i];
        float2 v = in2[(size_t)csrs[i] * C2 + q];
        ax += w * v.x; ay += w * v.y;
    }
    float2 r; r.x = ax; r.y = ay;
    ((float2*)out)[(size_t)p * C2 + q] = r;
}

// ---------------- pull gather, scalar (odd C) ----------------
template <int C>
__global__ void pull_kernel(const float* __restrict__ in, const int* __restrict__ rowptr,
                            const int* __restrict__ csrs, const float* __restrict__ csrw,
                            float* __restrict__ out)
{
    int id = blockIdx.x * 256 + threadIdx.x;
    if (id >= NND * C) return;
    int p = id / C, c = id % C;
    int beg = rowptr[p], end = rowptr[p + 1];
    float acc = 0.f;
    for (int i = beg; i < end; i++)
        acc += csrw[i] * in[(size_t)csrs[i] * C + c];
    out[id] = acc;
}

// ---------------- node-per-thread matmul + bias + relu, W staged in LDS ----------
template <int Cin, int Cout>
__global__ __launch_bounds__(128)
void matmul_node_kernel(const float* __restrict__ in, const float* __restrict__ W,
                        const float* __restrict__ bias, float* __restrict__ out)
{
    constexpr int CoutP = (Cout + 3) & ~3;
    __shared__ __align__(16) float wl[Cin * CoutP];
    __shared__ float bl[CoutP];
    const int t = threadIdx.x;
    const int br = blockIdx.y;
    const float* Wb = W + (size_t)br * Cin * Cout;
    for (int l = t; l < Cin * CoutP; l += 128) {
        int c = l / CoutP, o = l % CoutP;
        wl[l] = (o < Cout) ? Wb[c * Cout + o] : 0.f;
    }
    if (t < CoutP) bl[t] = (t < Cout) ? bias[br * Cout + t] : 0.f;
    __syncthreads();
    int p = blockIdx.x * 128 + t;
    if (p >= NND) return;
    float acc[CoutP];
#pragma unroll
    for (int o = 0; o < CoutP; o++) acc[o] = bl[o];
    const float* row = in + (size_t)br * NND * Cin + (size_t)p * Cin;
    if constexpr (Cin % 4 == 0) {
        const float4* row4 = (const float4*)row;
#pragma unroll
        for (int c4 = 0; c4 < Cin / 4; c4++) {
            float4 f4 = row4[c4];
            float fv[4] = {f4.x, f4.y, f4.z, f4.w};
#pragma unroll
            for (int cc = 0; cc < 4; cc++) {
                const float4* w4 = (const float4*)&wl[(c4 * 4 + cc) * CoutP];
#pragma unroll
                for (int oq = 0; oq < CoutP / 4; oq++) {
                    float4 wv = w4[oq];
                    acc[oq * 4 + 0] += fv[cc] * wv.x;
                    acc[oq * 4 + 1] += fv[cc] * wv.y;
                    acc[oq * 4 + 2] += fv[cc] * wv.z;
                    acc[oq * 4 + 3] += fv[cc] * wv.w;
                }
            }
        }
    } else if constexpr (Cin % 2 == 0) {
        const float2* row2 = (const float2*)row;
#pragma unroll
        for (int c2 = 0; c2 < Cin / 2; c2++) {
            float2 f2 = row2[c2];
            float fv[2] = {f2.x, f2.y};
#pragma unroll
            for (int cc = 0; cc < 2; cc++) {
                const float4* w4 = (const float4*)&wl[(c2 * 2 + cc) * CoutP];
#pragma unroll
                for (int oq = 0; oq < CoutP / 4; oq++) {
                    float4 wv = w4[oq];
                    acc[oq * 4 + 0] += fv[cc] * wv.x;
                    acc[oq * 4 + 1] += fv[cc] * wv.y;
                    acc[oq * 4 + 2] += fv[cc] * wv.z;
                    acc[oq * 4 + 3] += fv[cc] * wv.w;
                }
            }
        }
    } else {
#pragma unroll
        for (int c = 0; c < Cin; c++) {
            float f = row[c];
            const float4* w4 = (const float4*)&wl[c * CoutP];
#pragma unroll
            for (int oq = 0; oq < CoutP / 4; oq++) {
                float4 wv = w4[oq];
                acc[oq * 4 + 0] += f * wv.x;
                acc[oq * 4 + 1] += f * wv.y;
                acc[oq * 4 + 2] += f * wv.z;
                acc[oq * 4 + 3] += f * wv.w;
            }
        }
    }
    float* op = out + (size_t)br * NND * Cout + (size_t)p * Cout;
    if constexpr (Cout % 2 == 0) {
#pragma unroll
        for (int o2 = 0; o2 < Cout / 2; o2++) {
            float2 r;
            r.x = acc[o2 * 2] > 0.f ? acc[o2 * 2] : 0.f;
            r.y = acc[o2 * 2 + 1] > 0.f ? acc[o2 * 2 + 1] : 0.f;
            ((float2*)op)[o2] = r;
        }
    } else {
#pragma unroll
        for (int o = 0; o < Cout; o++) op[o] = acc[o] > 0.f ? acc[o] : 0.f;
    }
}

// ---------------- K6: press conv (3ch,K=3,SAME over 54) + BN2 stats ----------------
__global__ void press_stats_kernel(const float* __restrict__ H2, const float* __restrict__ pw,
                                   const float* __restrict__ pb, float* __restrict__ PRS,
                                   float* __restrict__ st2)
{
    __shared__ float ls[54], lq[54];
    int t = threadIdx.x;
    if (t < 54) { ls[t] = 0.f; lq[t] = 0.f; }
    __syncthreads();
    float pwf[9];
#pragma unroll
    for (int q = 0; q < 9; q++) pwf[q] = pw[q];
    float pbf = pb[0];
    const size_t NM = (size_t)NND * 54;
    size_t base = (size_t)blockIdx.x * 6912;
    for (int q = 0; q < 27; q++) {
        size_t idx = base + q * 256 + t;
        if (idx < NM) {
            int p = (int)(idx / 54), h = (int)(idx % 54);
            float sum = pbf;
#pragma unroll
            for (int i = 0; i < 3; i++)
#pragma unroll
                for (int k = 0; k < 3; k++) {
                    int hh = h + k - 1;
                    if (hh >= 0 && hh < 54)
                        sum += pwf[i * 3 + k] * H2[(size_t)i * NM + (size_t)p * 54 + hh];
                }
            PRS[idx] = sum;
            atomicAdd(&ls[h], sum); atomicAdd(&lq[h], sum * sum);
        }
    }
    __syncthreads();
    if (t < 54) {
        unsafeAtomicAdd(&st2[t], ls[t]);
        unsafeAtomicAdd(&st2[54 + t], lq[t]);
    }
}

// ---------------- K8: emd = affine(pressed) ----------------
__global__ void emd_kernel(float* __restrict__ PRS, const float* __restrict__ sc2,
                           const float* __restrict__ sh2, float* __restrict__ outp)
{
    int id = blockIdx.x * 256 + threadIdx.x;
    if (id >= NND * 54) return;
    int h = id % 54;
    float v = PRS[id] * sc2[h] + sh2[h];
    PRS[id] = v;
    outp[id] = v;
}

// ---------------- K15: graph pooling, block per graph, no atomics ----------------
__global__ void pool_kernel(const float* __restrict__ H1, const float* __restrict__ H2j,
                            const float* __restrict__ H3, const int* __restrict__ gr,
                            float* __restrict__ HG)
{
    __shared__ float part[4][75];
    int t = threadIdx.x;   // 300 = 75 x 4
    int c = t % 75, sub = t / 75;
    int g = blockIdx.x;
    int s = gr[g], e = gr[g + 1];
    float acc = 0.f;
    for (int p = s + sub; p < e; p += 4) {
        float v;
        if (c < 34)      v = H1[(size_t)p * 34 + c];
        else if (c < 59) v = H2j[(size_t)p * 25 + (c - 34)];
        else             v = H3[(size_t)p * 16 + (c - 59)];
        acc += v;
    }
    part[sub][c] = acc;
    __syncthreads();
    if (t < 75) HG[g * 75 + t] = part[0][t] + part[1][t] + part[2][t] + part[3][t];
}

// ---------------- K16: BN3 + cls matmuls, single block ----------------
__global__ void final_kernel(const float* __restrict__ HG, const float* __restrict__ g3,
                             const float* __restrict__ b3,
                             const float* __restrict__ w1, const float* __restrict__ b1,
                             const float* __restrict__ w2, const float* __restrict__ b2,
                             float* __restrict__ outp)
{
    __shared__ float hg[64 * 75];
    __shared__ float o1[64 * 120];
    __shared__ float sc[75], sh[75];
    int t = threadIdx.x;   // 512
    for (int idx = t; idx < 64 * 75; idx += 512) hg[idx] = HG[idx];
    __syncthreads();
    if (t < 75) {
        float s = 0.f, q = 0.f;
        for (int r = 0; r < 64; r++) { float v = hg[r * 75 + t]; s += v; q += v * v; }
        float m = s / 64.f, var = q / 64.f - m * m;
        float rs = rsqrtf(var + EPSV);
        float scale = g3[t] * rs;
        sc[t] = scale; sh[t] = b3[t] - m * scale;
    }
    __syncthreads();
    for (int idx = t; idx < 64 * 75; idx += 512) { int c = idx % 75; hg[idx] = hg[idx] * sc[c] + sh[c]; }
    __syncthreads();
    for (int idx = t; idx < 64 * 120; idx += 512) {
        int r = idx / 120, o = idx % 120;
        float a = b1[o];
        for (int c = 0; c < 75; c++) a += hg[r * 75 + c] * w1[c * 120 + o];
        o1[idx] = a;
    }
    __syncthreads();
    for (int idx = t; idx < 640; idx += 512) {
        int r = idx / 10, o = idx % 10;
        float a = b2[o];
        for (int k = 0; k < 120; k++) a += o1[r * 120 + k] * w2[k * 10 + o];
        outp[idx] = a;
    }
}

extern "C" void kernel_launch(void* const* d_in, const int* in_sizes, int n_in,
                              void* d_out, int out_size, void* d_ws, size_t ws_size,
                              hipStream_t stream)
{
    (void)in_sizes; (void)n_in; (void)out_size;
    const float* nf     = (const float*)d_in[0];
    const float* ew     = (const float*)d_in[1];
    const float* conv_w = (const float*)d_in[2];
    const float* conv_b = (const float*)d_in[3];
    const float* gcn_w  = (const float*)d_in[4];
    const float* gcn_b  = (const float*)d_in[5];
    const float* bn1_g = (const float*)d_in[6],  *bn1_b = (const float*)d_in[7];
    const float* bn2_g = (const float*)d_in[8],  *bn2_b = (const float*)d_in[9];
    const float* bn3_g = (const float*)d_in[10], *bn3_b = (const float*)d_in[11];
    const float* press_w = (const float*)d_in[12], *press_b = (const float*)d_in[13];
    const float* jk_w1 = (const float*)d_in[14], *jk_b1 = (const float*)d_in[15];
    const float* jk_w2 = (const float*)d_in[16], *jk_b2 = (const float*)d_in[17];
    const float* jk_w3 = (const float*)d_in[18], *jk_b3 = (const float*)d_in[19];
    const float* cls1_w = (const float*)d_in[20], *cls1_b = (const float*)d_in[21];
    const float* cls2_w = (const float*)d_in[22], *cls2_b = (const float*)d_in[23];
    const int* esrc = (const int*)d_in[24];
    const int* edst = (const int*)d_in[25];
    const int* gid  = (const int*)d_in[26];
    float* out = (float*)d_out;   // fp32 outputs: (logits[640], emd[2.7M])

    float* ws = (float*)d_ws;
    const size_t NM = (size_t)NND * 96;
    const size_t N54 = (size_t)NND * 54;
    float* X   = ws;                 // 3*NM   (nfT during conv; AGG after)
    float* Y   = X + 3 * NM;         // 3*NM   (jk buffers later)
    float* H2c = Y + 3 * NM;         // 3*N54
    float* PRS = H2c + 3 * N54;      // N54
    float* ST1 = PRS + N54;          // 576
    float* SC1 = ST1 + 576;          // 288
    float* SH1 = SC1 + 288;          // 288
    float* ST2 = SH1 + 288;          // 108
    float* SC2 = ST2 + 108;          // 54
    float* SH2 = SC2 + 54;           // 54
    float* HG  = SH2 + 54;           // 4800
    // CSR-by-dst + pooling scratch
    int* CNT    = (int*)(HG + 4800);     // 50000
    int* ROWPTR = CNT + NND;             // 50001
    int* CURSOR = ROWPTR + NND + 1;      // 50000
    int* CSRS   = CURSOR + NND;          // 800000
    float* CSRW = (float*)(CSRS + NED);  // 800000
    int* BSUM   = (int*)(CSRW + NED);    // 64 (49 used)
    int* GR     = BSUM + 64;             // 65
    size_t need = (size_t)((float*)(GR + 65) - ws) * sizeof(float);
    if (ws_size < need) return;      // ws too small -> fail loudly in validation

    // aliases
    float* nfT  = X;                 // [128][NSTR] padded — X region; dead once conv_y done
    float* AGG  = X;                 // after conv_y, pull_bn writes here
    float* AGG1 = Y;                           // N*54 (Y dead after pull_bn)
    float* H1j  = AGG1 + N54;                  // N*34
    float* AGG2 = H1j + (size_t)NND * 34;      // N*34
    float* H2j  = AGG2 + (size_t)NND * 34;     // N*25
    float* AGG3 = H2j + (size_t)NND * 25;      // N*25
    float* H3j  = AGG3 + (size_t)NND * 25;     // N*16

    // zero stats (ST1..SH2 = 1368 floats) and CSR histogram
    hipMemsetAsync(ST1, 0, 1368 * sizeof(float), stream);
    hipMemsetAsync(CNT, 0, NND * sizeof(int), stream);

    // CSR build (multi-block scan) + graph ranges
    hist_kernel<<<(NED + 255) / 256, 256, 0, stream>>>(edst, CNT);
    scanA_kernel<<<49, 256, 0, stream>>>(CNT, BSUM);
    scanB_kernel<<<1, 64, 0, stream>>>(BSUM, ROWPTR, 49);
    scanC_kernel<<<49, 1024, 0, stream>>>(CNT, BSUM, ROWPTR, CURSOR);
    fill_kernel<<<(NED + 255) / 256, 256, 0, stream>>>(esrc, edst, ew, CURSOR, CSRS, CSRW);
    grstart_kernel<<<1, 128, 0, stream>>>(gid, GR);

    // K0: transpose node feats into padded [c][4+p] (X region) + zero guard bands
    transpose_kernel<<<dim3((NND + 31) / 32, 4), 256, 0, stream>>>(nf, nfT);
    pad_kernel<<<1, 1024, 0, stream>>>(nfT);

    // K1+K2: fused dilated convs (all 3 branches) + cross-connect + BN1 stats
    conv_y_stats_kernel<<<dim3(12, 49), 256, 0, stream>>>(nfT, conv_w, conv_b, Y, ST1);
    bn_finalize_kernel<<<1, 512, 0, stream>>>(ST1, bn1_g, bn1_b, SC1, SH1, 288, 96);

    // K4: pull GCN aggregate, 3 branches fused, float4 channels (overwrites nfT)
    pull_bn_kernel<<<(NND * 24 + 255) / 256, 256, 0, stream>>>(
        Y, ROWPTR, CSRS, CSRW, SC1, SH1, AGG);

    // K5: GCN matmul + relu, node-per-thread, 3 branches via gridDim.y
    matmul_node_kernel<96, 54><<<dim3((NND + 127) / 128, 3), 128, 0, stream>>>(
        AGG, gcn_w, gcn_b, H2c);

    // K6/K7/K8: press + BN2 + emd out (fp32 at element offset 640)
    press_stats_kernel<<<(int)((N54 + 6911) / 6912), 256, 0, stream>>>(H2c, press_w, press_b, PRS, ST2);
    bn_finalize_kernel<<<1, 512, 0, stream>>>(ST2, bn2_g, bn2_b, SC2, SH2, 54, 54);
    emd_kernel<<<(int)((N54 + 255) / 256), 256, 0, stream>>>(PRS, SC2, SH2, out + 640);

    // JK layer 1 (Y region dead -> jk buffers)
    pull2_kernel<54><<<(NND * 27 + 255) / 256, 256, 0, stream>>>(PRS, ROWPTR, CSRS, CSRW, AGG1);
    matmul_node_kernel<54, 34><<<dim3((NND + 127) / 128, 1), 128, 0, stream>>>(
        AGG1, jk_w1, jk_b1, H1j);

    // JK layer 2
    pull2_kernel<34><<<(NND * 17 + 255) / 256, 256, 0, stream>>>(H1j, ROWPTR, CSRS, CSRW, AGG2);
    matmul_node_kernel<34, 25><<<dim3((NND + 127) / 128, 1), 128, 0, stream>>>(
        AGG2, jk_w2, jk_b2, H2j);

    // JK layer 3
    pull_kernel<25><<<(NND * 25 + 255) / 256, 256, 0, stream>>>(H2j, ROWPTR, CSRS, CSRW, AGG3);
    matmul_node_kernel<25, 16><<<dim3((NND + 127) / 128, 1), 128, 0, stream>>>(
        AGG3, jk_w3, jk_b3, H3j);

    // pooling (block per graph, no atomics) + final
    pool_kernel<<<NGR, 300, 0, stream>>>(H1j, H2j, H3j, GR, HG);
    final_kernel<<<1, 512, 0, stream>>>(HG, bn3_g, bn3_b, cls1_w, cls1_b, cls2_w, cls2_b, out);
}

// Round 11
// 988.841 us; speedup vs baseline: 1.0474x; 1.0474x over previous
//
#include <hip/hip_runtime.h>
#include <hip/hip_bf16.h>

#define NND 50000
#define NED 800000
#define NGR 64
#define EPSV 1e-5f
#define NSTR (NND + 8)   // padded column stride for nfT (4-elem zero guards)

// ---------------- CSR build: histogram / 3-phase scan / fill ----------------
__global__ void hist_kernel(const int* __restrict__ dst, int* __restrict__ cnt)
{
    int e = blockIdx.x * 256 + threadIdx.x;
    if (e < NED) atomicAdd(&cnt[dst[e]], 1);
}

__global__ void scanA_kernel(const int* __restrict__ cnt, int* __restrict__ bsum)
{
    __shared__ int buf[256];
    int t = threadIdx.x, base = blockIdx.x * 1024;
    int s = 0;
    for (int i = t; i < 1024; i += 256) {
        int idx = base + i;
        s += (idx < NND) ? cnt[idx] : 0;
    }
    buf[t] = s; __syncthreads();
    for (int off = 128; off; off >>= 1) {
        if (t < off) buf[t] += buf[t + off];
        __syncthreads();
    }
    if (t == 0) bsum[blockIdx.x] = buf[0];
}

__global__ void scanB_kernel(int* __restrict__ bsum, int* __restrict__ rowptr, int nb)
{
    if (threadIdx.x == 0) {
        int acc = 0;
        for (int i = 0; i < nb; i++) { int v = bsum[i]; bsum[i] = acc; acc += v; }
        rowptr[NND] = acc;
    }
}

__global__ void scanC_kernel(const int* __restrict__ cnt, const int* __restrict__ bsum,
                             int* __restrict__ rowptr, int* __restrict__ cursor)
{
    __shared__ int buf[1024];
    int t = threadIdx.x, idx = blockIdx.x * 1024 + t;
    int v = (idx < NND) ? cnt[idx] : 0;
    buf[t] = v; __syncthreads();
    for (int off = 1; off < 1024; off <<= 1) {
        int x = (t >= off) ? buf[t - off] : 0;
        __syncthreads();
        buf[t] += x;
        __syncthreads();
    }
    if (idx < NND) {
        int excl = buf[t] - v + bsum[blockIdx.x];
        rowptr[idx] = excl; cursor[idx] = excl;
    }
}

__global__ void fill_kernel(const int* __restrict__ src, const int* __restrict__ dst,
                            const float* __restrict__ ew, int* __restrict__ cursor,
                            int* __restrict__ csrs, float* __restrict__ csrw)
{
    int e = blockIdx.x * 256 + threadIdx.x;
    if (e < NED) {
        int pos = atomicAdd(&cursor[dst[e]], 1);
        csrs[pos] = src[e];
        csrw[pos] = ew[e];
    }
}

// ---------------- graph ranges via binary search on sorted graph_ids ----------------
__global__ void grstart_kernel(const int* __restrict__ gid, int* __restrict__ gr)
{
    int t = threadIdx.x;
    if (t > NGR) return;
    if (t == NGR) { gr[NGR] = NND; return; }
    int lo = 0, hi = NND;
    while (lo < hi) { int mid = (lo + hi) >> 1; if (gid[mid] < t) lo = mid + 1; else hi = mid; }
    gr[t] = lo;
}

// ---------------- K0: transpose node_feats [p][c] -> nfT [c][4+p] (padded) ---------
__global__ void transpose_kernel(const float* __restrict__ nf, float* __restrict__ nfT)
{
    __shared__ float tile[32][33];
    int tx = threadIdx.x & 31, ty = threadIdx.x >> 5;   // 32 x 8
    int p0 = blockIdx.x * 32, c0 = blockIdx.y * 32;
#pragma unroll
    for (int i = 0; i < 4; i++) {
        int p = p0 + ty + i * 8;
        if (p < NND) tile[ty + i * 8][tx] = nf[(size_t)p * 128 + c0 + tx];
    }
    __syncthreads();
#pragma unroll
    for (int i = 0; i < 4; i++) {
        int c = c0 + ty + i * 8;
        int p = p0 + tx;
        if (p < NND) nfT[(size_t)c * NSTR + 4 + p] = tile[tx][ty + i * 8];
    }
}

// zero the 4-elem guard bands of each padded column
__global__ void pad_kernel(float* __restrict__ nfT)
{
    int t = threadIdx.x;           // 1024 = 128 ch x 8 pad slots
    int c = t >> 3, i = t & 7;
    size_t off = (size_t)c * NSTR + (i < 4 ? i : (NND + i));  // 0..3 and NND+4..NND+7
    nfT[off] = 0.f;
}

// ---------------- fused conv + cross-connect(relu) + BN1 stats ----------------
// og = 4 out-ch per block (24 groups), 4 nodes/thread — high-occupancy shape.
template <int D>
__device__ __forceinline__ void conv_tap4(const float4& lo, const float4& mi, const float4& hi,
                                          const float* __restrict__ wl, int c,
                                          float (&acc)[4][4])
{
    float f0[4], f1[4], f2[4];
    f1[0] = mi.x; f1[1] = mi.y; f1[2] = mi.z; f1[3] = mi.w;
    if (D == 1) {
        f0[0] = lo.w; f0[1] = mi.x; f0[2] = mi.y; f0[3] = mi.z;
        f2[0] = mi.y; f2[1] = mi.z; f2[2] = mi.w; f2[3] = hi.x;
    } else if (D == 2) {
        f0[0] = lo.z; f0[1] = lo.w; f0[2] = mi.x; f0[3] = mi.y;
        f2[0] = mi.z; f2[1] = mi.w; f2[2] = hi.x; f2[3] = hi.y;
    } else {
        f0[0] = lo.y; f0[1] = lo.z; f0[2] = lo.w; f0[3] = mi.x;
        f2[0] = mi.w; f2[1] = hi.x; f2[2] = hi.y; f2[3] = hi.z;
    }
    const int BR = D - 1;
    const float4 a0 = *(const float4*)&wl[((BR * 3 + 0) * 128 + c) * 4];
    const float4 a1 = *(const float4*)&wl[((BR * 3 + 1) * 128 + c) * 4];
    const float4 a2 = *(const float4*)&wl[((BR * 3 + 2) * 128 + c) * 4];
#pragma unroll
    for (int i = 0; i < 4; i++) {
        acc[0][i] += f0[i] * a0.x + f1[i] * a1.x + f2[i] * a2.x;
        acc[1][i] += f0[i] * a0.y + f1[i] * a1.y + f2[i] * a2.y;
        acc[2][i] += f0[i] * a0.z + f1[i] * a1.z + f2[i] * a2.z;
        acc[3][i] += f0[i] * a0.w + f1[i] * a1.w + f2[i] * a2.w;
    }
}

__global__ __launch_bounds__(256)
void conv_y_stats_kernel(const float* __restrict__ nfT, const float* __restrict__ cw,
                         const float* __restrict__ cb, float* __restrict__ Y,
                         float* __restrict__ st1)
{
    __shared__ __align__(16) float wl[3 * 3 * 128 * 4];   // [br][k][c][j4] : 18 KB
    const int t  = threadIdx.x;
    const int og = blockIdx.x;   // 0..23 (4 out channels)
    for (int l = t; l < 3 * 3 * 128 * 4; l += 256) {
        int j = l & 3; int c = (l >> 2) & 127; int kb = l >> 9;  // kb = br*3+k
        int k = kb % 3, br = kb / 3;
        wl[l] = cw[(((size_t)br * 96 + og * 4 + j) * 128 + c) * 3 + k];
    }
    __syncthreads();
    const int pq = blockIdx.y * 1024 + t * 4;
    float acc[3][4][4];
#pragma unroll
    for (int br = 0; br < 3; br++)
#pragma unroll
        for (int j = 0; j < 4; j++) {
            float b = cb[br * 96 + og * 4 + j];
#pragma unroll
            for (int i = 0; i < 4; i++) acc[br][j][i] = b;
        }
    for (int c = 0; c < 128; c++) {
        const float* col = nfT + (size_t)c * NSTR + 4;
        float4 lo = *(const float4*)(col + pq - 4);
        float4 mi = *(const float4*)(col + pq);
        float4 hi = *(const float4*)(col + pq + 4);
        conv_tap4<1>(lo, mi, hi, wl, c, acc[0]);
        conv_tap4<2>(lo, mi, hi, wl, c, acc[1]);
        conv_tap4<3>(lo, mi, hi, wl, c, acc[2]);
    }
    // cross-connect in-register: y[br] = relu(x[br]) + x[(br+1)%3]
#pragma unroll
    for (int j = 0; j < 4; j++)
#pragma unroll
        for (int i = 0; i < 4; i++) {
            float a0 = acc[0][j][i], a1 = acc[1][j][i], a2 = acc[2][j][i];
            acc[0][j][i] = (a0 > 0.f ? a0 : 0.f) + a1;
            acc[1][j][i] = (a1 > 0.f ? a1 : 0.f) + a2;
            acc[2][j][i] = (a2 > 0.f ? a2 : 0.f) + a0;
        }
    bool val[4];
#pragma unroll
    for (int i = 0; i < 4; i++) val[i] = (pq + i) < NND;
    // BN1 stats: shuffle-reduce per (br, j), lane0 atomics
    const size_t NM = (size_t)NND * 96;
#pragma unroll
    for (int br = 0; br < 3; br++)
#pragma unroll
        for (int j = 0; j < 4; j++) {
            float s = 0.f, q = 0.f;
#pragma unroll
            for (int i = 0; i < 4; i++)
                if (val[i]) { float v = acc[br][j][i]; s += v; q += v * v; }
            for (int off = 32; off; off >>= 1) {
                s += __shfl_down(s, off, 64);
                q += __shfl_down(q, off, 64);
            }
            if ((t & 63) == 0) {
                unsafeAtomicAdd(&st1[br * 96 + og * 4 + j], s);
                unsafeAtomicAdd(&st1[288 + br * 96 + og * 4 + j], q);
            }
        }
    // write Y (one float4 per (br, node))
#pragma unroll
    for (int br = 0; br < 3; br++)
#pragma unroll
        for (int i = 0; i < 4; i++) {
            if (!val[i]) continue;
            float* yo = Y + (size_t)br * NM + (size_t)(pq + i) * 96 + og * 4;
            float4 v;
            v.x = acc[br][0][i]; v.y = acc[br][1][i]; v.z = acc[br][2][i]; v.w = acc[br][3][i];
            *(float4*)yo = v;
        }
}

// ---------------- BN finalize ----------------
__global__ void bn_finalize_kernel(const float* __restrict__ st, const float* __restrict__ g,
                                   const float* __restrict__ b,
                                   float* __restrict__ sc, float* __restrict__ sh,
                                   int C, int gmod)
{
    int t = threadIdx.x;
    if (t >= C) return;
    float mean = st[t] / (float)NND;
    float var  = st[C + t] / (float)NND - mean * mean;
    float rs = rsqrtf(var + EPSV);
    float gg = g[t % gmod], bb = b[t % gmod];
    float s = gg * rs;
    sc[t] = s; sh[t] = bb - mean * s;
}

// ---------------- K4: pull GCN aggregate, 3 branches fused, float4 channels ------
__global__ void pull_bn_kernel(const float* __restrict__ Y, const int* __restrict__ rowptr,
                               const int* __restrict__ csrs, const float* __restrict__ csrw,
                               const float* __restrict__ sc1, const float* __restrict__ sh1,
                               float* __restrict__ AGG)
{
    int id = blockIdx.x * 256 + threadIdx.x;
    if (id >= NND * 24) return;
    int p = id / 24, q = id % 24;
    const float4* Y4 = (const float4*)Y;
    const size_t NQ = (size_t)NND * 24;
    int beg = rowptr[p], end = rowptr[p + 1];
    float a0x=0,a0y=0,a0z=0,a0w=0, a1x=0,a1y=0,a1z=0,a1w=0, a2x=0,a2y=0,a2z=0,a2w=0;
    float wsum = 0.f;
    for (int i = beg; i < end; i++) {
        float w = csrw[i];
        size_t off = (size_t)csrs[i] * 24 + q;
        float4 v0 = Y4[off];
        float4 v1 = Y4[NQ + off];
        float4 v2 = Y4[2 * NQ + off];
        a0x += w * v0.x; a0y += w * v0.y; a0z += w * v0.z; a0w += w * v0.w;
        a1x += w * v1.x; a1y += w * v1.y; a1z += w * v1.z; a1w += w * v1.w;
        a2x += w * v2.x; a2y += w * v2.y; a2z += w * v2.z; a2w += w * v2.w;
        wsum += w;
    }
    const float4* S4 = (const float4*)sc1;
    const float4* H4 = (const float4*)sh1;
    float4* AG4 = (float4*)AGG;
    size_t ob = (size_t)p * 24 + q;
    {
        float4 s = S4[q], h = H4[q], r;
        r.x = s.x * a0x + h.x * wsum; r.y = s.y * a0y + h.y * wsum;
        r.z = s.z * a0z + h.z * wsum; r.w = s.w * a0w + h.w * wsum;
        AG4[ob] = r;
    }
    {
        float4 s = S4[24 + q], h = H4[24 + q], r;
        r.x = s.x * a1x + h.x * wsum; r.y = s.y * a1y + h.y * wsum;
        r.z = s.z * a1z + h.z * wsum; r.w = s.w * a1w + h.w * wsum;
        AG4[NQ + ob] = r;
    }
    {
        float4 s = S4[48 + q], h = H4[48 + q], r;
        r.x = s.x * a2x + h.x * wsum; r.y = s.y * a2y + h.y * wsum;
        r.z = s.z * a2z + h.z * wsum; r.w = s.w * a2w + h.w * wsum;
        AG4[2 * NQ + ob] = r;
    }
}

// ---------------- pull gather, float2-vectorized (C even) ----------------
template <int C>
__global__ void pull2_kernel(const float* __restrict__ in, const int* __restrict__ rowptr,
                             const int* __restrict__ csrs, const float* __restrict__ csrw,
                             float* __restrict__ out)
{
    constexpr int C2 = C / 2;
    int id = blockIdx.x * 256 + threadIdx.x;
    if (id >= NND * C2) return;
    int p = id / C2, q = id % C2;
    const float2* in2 = (const float2*)in;
    int beg = rowptr[p], end = rowptr[p + 1];
    float ax = 0.f, ay = 0.f;
    for (int i = beg; i < end; i++) {
        float w = csrw[i];
        float2 v = in2[(size_t)csrs[i] * C2 + q];
        ax += w * v.x; ay += w * v.y;
    }
    float2 r; r.x = ax; r.y = ay;
    ((float2*)out)[(size_t)p * C2 + q] = r;
}

// ---------------- pull gather, scalar (odd C) ----------------
template <int C>
__global__ void pull_kernel(const float* __restrict__ in, const int* __restrict__ rowptr,
                            const int* __restrict__ csrs, const float* __restrict__ csrw,
                            float* __restrict__ out)
{
    int id = blockIdx.x * 256 + threadIdx.x;
    if (id >= NND * C) return;
    int p = id / C, c = id % C;
    int beg = rowptr[p], end = rowptr[p + 1];
    float acc = 0.f;
    for (int i = beg; i < end; i++)
        acc += csrw[i] * in[(size_t)csrs[i] * C + c];
    out[id] = acc;
}

// ---------------- node-per-thread matmul + bias + relu, W staged in LDS ----------
template <int Cin, int Cout>
__global__ __launch_bounds__(128)
void matmul_node_kernel(const float* __restrict__ in, const float* __restrict__ W,
                        const float* __restrict__ bias, float* __restrict__ out)
{
    constexpr int CoutP = (Cout + 3) & ~3;
    __shared__ __align__(16) float wl[Cin * CoutP];
    __shared__ float bl[CoutP];
    const int t = threadIdx.x;
    const int br = blockIdx.y;
    const float* Wb = W + (size_t)br * Cin * Cout;
    for (int l = t; l < Cin * CoutP; l += 128) {
        int c = l / CoutP, o = l % CoutP;
        wl[l] = (o < Cout) ? Wb[c * Cout + o] : 0.f;
    }
    if (t < CoutP) bl[t] = (t < Cout) ? bias[br * Cout + t] : 0.f;
    __syncthreads();
    int p = blockIdx.x * 128 + t;
    if (p >= NND) return;
    float acc[CoutP];
#pragma unroll
    for (int o = 0; o < CoutP; o++) acc[o] = bl[o];
    const float* row = in + (size_t)br * NND * Cin + (size_t)p * Cin;
    if constexpr (Cin % 4 == 0) {
        const float4* row4 = (const float4*)row;
#pragma unroll
        for (int c4 = 0; c4 < Cin / 4; c4++) {
            float4 f4 = row4[c4];
            float fv[4] = {f4.x, f4.y, f4.z, f4.w};
#pragma unroll
            for (int cc = 0; cc < 4; cc++) {
                const float4* w4 = (const float4*)&wl[(c4 * 4 + cc) * CoutP];
#pragma unroll
                for (int oq = 0; oq < CoutP / 4; oq++) {
                    float4 wv = w4[oq];
                    acc[oq * 4 + 0] += fv[cc] * wv.x;
                    acc[oq * 4 + 1] += fv[cc] * wv.y;
                    acc[oq * 4 + 2] += fv[cc] * wv.z;
                    acc[oq * 4 + 3] += fv[cc] * wv.w;
                }
            }
        }
    } else if constexpr (Cin % 2 == 0) {
        const float2* row2 = (const float2*)row;
#pragma unroll
        for (int c2 = 0; c2 < Cin / 2; c2++) {
            float2 f2 = row2[c2];
            float fv[2] = {f2.x, f2.y};
#pragma unroll
            for (int cc = 0; cc < 2; cc++) {
                const float4* w4 = (const float4*)&wl[(c2 * 2 + cc) * CoutP];
#pragma unroll
                for (int oq = 0; oq < CoutP / 4; oq++) {
                    float4 wv = w4[oq];
                    acc[oq * 4 + 0] += fv[cc] * wv.x;
                    acc[oq * 4 + 1] += fv[cc] * wv.y;
                    acc[oq * 4 + 2] += fv[cc] * wv.z;
                    acc[oq * 4 + 3] += fv[cc] * wv.w;
                }
            }
        }
    } else {
#pragma unroll
        for (int c = 0; c < Cin; c++) {
            float f = row[c];
            const float4* w4 = (const float4*)&wl[c * CoutP];
#pragma unroll
            for (int oq = 0; oq < CoutP / 4; oq++) {
                float4 wv = w4[oq];
                acc[oq * 4 + 0] += f * wv.x;
                acc[oq * 4 + 1] += f * wv.y;
                acc[oq * 4 + 2] += f * wv.z;
                acc[oq * 4 + 3] += f * wv.w;
            }
        }
    }
    float* op = out + (size_t)br * NND * Cout + (size_t)p * Cout;
    if constexpr (Cout % 2 == 0) {
#pragma unroll
        for (int o2 = 0; o2 < Cout / 2; o2++) {
            float2 r;
            r.x = acc[o2 * 2] > 0.f ? acc[o2 * 2] : 0.f;
            r.y = acc[o2 * 2 + 1] > 0.f ? acc[o2 * 2 + 1] : 0.f;
            ((float2*)op)[o2] = r;
        }
    } else {
#pragma unroll
        for (int o = 0; o < Cout; o++) op[o] = acc[o] > 0.f ? acc[o] : 0.f;
    }
}

// ---------------- K6: press conv (3ch,K=3,SAME over 54) + BN2 stats ----------------
__global__ void press_stats_kernel(const float* __restrict__ H2, const float* __restrict__ pw,
                                   const float* __restrict__ pb, float* __restrict__ PRS,
                                   float* __restrict__ st2)
{
    __shared__ float ls[54], lq[54];
    int t = threadIdx.x;
    if (t < 54) { ls[t] = 0.f; lq[t] = 0.f; }
    __syncthreads();
    float pwf[9];
#pragma unroll
    for (int q = 0; q < 9; q++) pwf[q] = pw[q];
    float pbf = pb[0];
    const size_t NM = (size_t)NND * 54;
    size_t base = (size_t)blockIdx.x * 6912;
    for (int q = 0; q < 27; q++) {
        size_t idx = base + q * 256 + t;
        if (idx < NM) {
            int p = (int)(idx / 54), h = (int)(idx % 54);
            float sum = pbf;
#pragma unroll
            for (int i = 0; i < 3; i++)
#pragma unroll
                for (int k = 0; k < 3; k++) {
                    int hh = h + k - 1;
                    if (hh >= 0 && hh < 54)
                        sum += pwf[i * 3 + k] * H2[(size_t)i * NM + (size_t)p * 54 + hh];
                }
            PRS[idx] = sum;
            atomicAdd(&ls[h], sum); atomicAdd(&lq[h], sum * sum);
        }
    }
    __syncthreads();
    if (t < 54) {
        unsafeAtomicAdd(&st2[t], ls[t]);
        unsafeAtomicAdd(&st2[54 + t], lq[t]);
    }
}

// ---------------- K8: emd = affine(pressed) ----------------
__global__ void emd_kernel(float* __restrict__ PRS, const float* __restrict__ sc2,
                           const float* __restrict__ sh2, float* __restrict__ outp)
{
    int id = blockIdx.x * 256 + threadIdx.x;
    if (id >= NND * 54) return;
    int h = id % 54;
    float v = PRS[id] * sc2[h] + sh2[h];
    PRS[id] = v;
    outp[id] = v;
}

// ---------------- K15: graph pooling, block per graph, no atomics ----------------
__global__ void pool_kernel(const float* __restrict__ H1, const float* __restrict__ H2j,
                            const float* __restrict__ H3, const int* __restrict__ gr,
                            float* __restrict__ HG)
{
    __shared__ float part[4][75];
    int t = threadIdx.x;   // 300 = 75 x 4
    int c = t % 75, sub = t / 75;
    int g = blockIdx.x;
    int s = gr[g], e = gr[g + 1];
    float acc = 0.f;
    for (int p = s + sub; p < e; p += 4) {
        float v;
        if (c < 34)      v = H1[(size_t)p * 34 + c];
        else if (c < 59) v = H2j[(size_t)p * 25 + (c - 34)];
        else             v = H3[(size_t)p * 16 + (c - 59)];
        acc += v;
    }
    part[sub][c] = acc;
    __syncthreads();
    if (t < 75) HG[g * 75 + t] = part[0][t] + part[1][t] + part[2][t] + part[3][t];
}

// ---------------- K16: BN3 + cls matmuls, single block ----------------
__global__ void final_kernel(const float* __restrict__ HG, const float* __restrict__ g3,
                             const float* __restrict__ b3,
                             const float* __restrict__ w1, const float* __restrict__ b1,
                             const float* __restrict__ w2, const float* __restrict__ b2,
                             float* __restrict__ outp)
{
    __shared__ float hg[64 * 75];
    __shared__ float o1[64 * 120];
    __shared__ float sc[75], sh[75];
    int t = threadIdx.x;   // 512
    for (int idx = t; idx < 64 * 75; idx += 512) hg[idx] = HG[idx];
    __syncthreads();
    if (t < 75) {
        float s = 0.f, q = 0.f;
        for (int r = 0; r < 64; r++) { float v = hg[r * 75 + t]; s += v; q += v * v; }
        float m = s / 64.f, var = q / 64.f - m * m;
        float rs = rsqrtf(var + EPSV);
        float scale = g3[t] * rs;
        sc[t] = scale; sh[t] = b3[t] - m * scale;
    }
    __syncthreads();
    for (int idx = t; idx < 64 * 75; idx += 512) { int c = idx % 75; hg[idx] = hg[idx] * sc[c] + sh[c]; }
    __syncthreads();
    for (int idx = t; idx < 64 * 120; idx += 512) {
        int r = idx / 120, o = idx % 120;
        float a = b1[o];
        for (int c = 0; c < 75; c++) a += hg[r * 75 + c] * w1[c * 120 + o];
        o1[idx] = a;
    }
    __syncthreads();
    for (int idx = t; idx < 640; idx += 512) {
        int r = idx / 10, o = idx % 10;
        float a = b2[o];
        for (int k = 0; k < 120; k++) a += o1[r * 120 + k] * w2[k * 10 + o];
        outp[idx] = a;
    }
}

extern "C" void kernel_launch(void* const* d_in, const int* in_sizes, int n_in,
                              void* d_out, int out_size, void* d_ws, size_t ws_size,
                              hipStream_t stream)
{
    (void)in_sizes; (void)n_in; (void)out_size;
    const float* nf     = (const float*)d_in[0];
    const float* ew     = (const float*)d_in[1];
    const float* conv_w = (const float*)d_in[2];
    const float* conv_b = (const float*)d_in[3];
    const float* gcn_w  = (const float*)d_in[4];
    const float* gcn_b  = (const float*)d_in[5];
    const float* bn1_g = (const float*)d_in[6],  *bn1_b = (const float*)d_in[7];
    const float* bn2_g = (const float*)d_in[8],  *bn2_b = (const float*)d_in[9];
    const float* bn3_g = (const float*)d_in[10], *bn3_b = (const float*)d_in[11];
    const float* press_w = (const float*)d_in[12], *press_b = (const float*)d_in[13];
    const float* jk_w1 = (const float*)d_in[14], *jk_b1 = (const float*)d_in[15];
    const float* jk_w2 = (const float*)d_in[16], *jk_b2 = (const float*)d_in[17];
    const float* jk_w3 = (const float*)d_in[18], *jk_b3 = (const float*)d_in[19];
    const float* cls1_w = (const float*)d_in[20], *cls1_b = (const float*)d_in[21];
    const float* cls2_w = (const float*)d_in[22], *cls2_b = (const float*)d_in[23];
    const int* esrc = (const int*)d_in[24];
    const int* edst = (const int*)d_in[25];
    const int* gid  = (const int*)d_in[26];
    float* out = (float*)d_out;   // fp32 outputs: (logits[640], emd[2.7M])

    float* ws = (float*)d_ws;
    const size_t NM = (size_t)NND * 96;
    const size_t N54 = (size_t)NND * 54;
    float* X   = ws;                 // 3*NM   (nfT during conv; AGG after)
    float* Y   = X + 3 * NM;         // 3*NM   (jk buffers later)
    float* H2c = Y + 3 * NM;         // 3*N54
    float* PRS = H2c + 3 * N54;      // N54
    float* ST1 = PRS + N54;          // 576
    float* SC1 = ST1 + 576;          // 288
    float* SH1 = SC1 + 288;          // 288
    float* ST2 = SH1 + 288;          // 108
    float* SC2 = ST2 + 108;          // 54
    float* SH2 = SC2 + 54;           // 54
    float* HG  = SH2 + 54;           // 4800
    // CSR-by-dst + pooling scratch
    int* CNT    = (int*)(HG + 4800);     // 50000
    int* ROWPTR = CNT + NND;             // 50001
    int* CURSOR = ROWPTR + NND + 1;      // 50000
    int* CSRS   = CURSOR + NND;          // 800000
    float* CSRW = (float*)(CSRS + NED);  // 800000
    int* BSUM   = (int*)(CSRW + NED);    // 64 (49 used)
    int* GR     = BSUM + 64;             // 65
    size_t need = (size_t)((float*)(GR + 65) - ws) * sizeof(float);
    if (ws_size < need) return;      // ws too small -> fail loudly in validation

    // aliases
    float* nfT  = X;                 // [128][NSTR] padded — X region; dead once conv_y done
    float* AGG  = X;                 // after conv_y, pull_bn writes here
    float* AGG1 = Y;                           // N*54 (Y dead after pull_bn)
    float* H1j  = AGG1 + N54;                  // N*34
    float* AGG2 = H1j + (size_t)NND * 34;      // N*34
    float* H2j  = AGG2 + (size_t)NND * 34;     // N*25
    float* AGG3 = H2j + (size_t)NND * 25;      // N*25
    float* H3j  = AGG3 + (size_t)NND * 25;     // N*16

    // zero stats (ST1..SH2 = 1368 floats) and CSR histogram
    hipMemsetAsync(ST1, 0, 1368 * sizeof(float), stream);
    hipMemsetAsync(CNT, 0, NND * sizeof(int), stream);

    // CSR build (multi-block scan) + graph ranges
    hist_kernel<<<(NED + 255) / 256, 256, 0, stream>>>(edst, CNT);
    scanA_kernel<<<49, 256, 0, stream>>>(CNT, BSUM);
    scanB_kernel<<<1, 64, 0, stream>>>(BSUM, ROWPTR, 49);
    scanC_kernel<<<49, 1024, 0, stream>>>(CNT, BSUM, ROWPTR, CURSOR);
    fill_kernel<<<(NED + 255) / 256, 256, 0, stream>>>(esrc, edst, ew, CURSOR, CSRS, CSRW);
    grstart_kernel<<<1, 128, 0, stream>>>(gid, GR);

    // K0: transpose node feats into padded [c][4+p] (X region) + zero guard bands
    transpose_kernel<<<dim3((NND + 31) / 32, 4), 256, 0, stream>>>(nf, nfT);
    pad_kernel<<<1, 1024, 0, stream>>>(nfT);

    // K1+K2: fused dilated convs + cross-connect + BN1 stats (og=4, high occupancy)
    conv_y_stats_kernel<<<dim3(24, 49), 256, 0, stream>>>(nfT, conv_w, conv_b, Y, ST1);
    bn_finalize_kernel<<<1, 512, 0, stream>>>(ST1, bn1_g, bn1_b, SC1, SH1, 288, 96);

    // K4: pull GCN aggregate, 3 branches fused, float4 channels (overwrites nfT)
    pull_bn_kernel<<<(NND * 24 + 255) / 256, 256, 0, stream>>>(
        Y, ROWPTR, CSRS, CSRW, SC1, SH1, AGG);

    // K5: GCN matmul + relu, node-per-thread, 3 branches via gridDim.y
    matmul_node_kernel<96, 54><<<dim3((NND + 127) / 128, 3), 128, 0, stream>>>(
        AGG, gcn_w, gcn_b, H2c);

    // K6/K7/K8: press + BN2 + emd out (fp32 at element offset 640)
    press_stats_kernel<<<(int)((N54 + 6911) / 6912), 256, 0, stream>>>(H2c, press_w, press_b, PRS, ST2);
    bn_finalize_kernel<<<1, 512, 0, stream>>>(ST2, bn2_g, bn2_b, SC2, SH2, 54, 54);
    emd_kernel<<<(int)((N54 + 255) / 256), 256, 0, stream>>>(PRS, SC2, SH2, out + 640);

    // JK layer 1 (Y region dead -> jk buffers)
    pull2_kernel<54><<<(NND * 27 + 255) / 256, 256, 0, stream>>>(PRS, ROWPTR, CSRS, CSRW, AGG1);
    matmul_node_kernel<54, 34><<<dim3((NND + 127) / 128, 1), 128, 0, stream>>>(
        AGG1, jk_w1, jk_b1, H1j);

    // JK layer 2
    pull2_kernel<34><<<(NND * 17 + 255) / 256, 256, 0, stream>>>(H1j, ROWPTR, CSRS, CSRW, AGG2);
    matmul_node_kernel<34, 25><<<dim3((NND + 127) / 128, 1), 128, 0, stream>>>(
        AGG2, jk_w2, jk_b2, H2j);

    // JK layer 3
    pull_kernel<25><<<(NND * 25 + 255) / 256, 256, 0, stream>>>(H2j, ROWPTR, CSRS, CSRW, AGG3);
    matmul_node_kernel<25, 16><<<dim3((NND + 127) / 128, 1), 128, 0, stream>>>(
        AGG3, jk_w3, jk_b3, H3j);

    // pooling (block per graph, no atomics) + final
    pool_kernel<<<NGR, 300, 0, stream>>>(H1j, H2j, H3j, GR, HG);
    final_kernel<<<1, 512, 0, stream>>>(HG, bn3_g, bn3_b, cls1_w, cls1_b, cls2_w, cls2_b, out);
}

// Round 12
// 939.156 us; speedup vs baseline: 1.1028x; 1.0529x over previous
//
#include <hip/hip_runtime.h>
#include <hip/hip_bf16.h>

#define NND 50000
#define NED 800000
#define NGR 64
#define EPSV 1e-5f
#define NSTR (NND + 8)   // padded column stride for nfT (4-elem zero guards)

// ---------------- CSR build: histogram / 3-phase scan / fill ----------------
__global__ void hist_kernel(const int* __restrict__ dst, int* __restrict__ cnt)
{
    int e = blockIdx.x * 256 + threadIdx.x;
    if (e < NED) atomicAdd(&cnt[dst[e]], 1);
}

__global__ void scanA_kernel(const int* __restrict__ cnt, int* __restrict__ bsum)
{
    __shared__ int buf[256];
    int t = threadIdx.x, base = blockIdx.x * 1024;
    int s = 0;
    for (int i = t; i < 1024; i += 256) {
        int idx = base + i;
        s += (idx < NND) ? cnt[idx] : 0;
    }
    buf[t] = s; __syncthreads();
    for (int off = 128; off; off >>= 1) {
        if (t < off) buf[t] += buf[t + off];
        __syncthreads();
    }
    if (t == 0) bsum[blockIdx.x] = buf[0];
}

__global__ void scanB_kernel(int* __restrict__ bsum, int* __restrict__ rowptr, int nb)
{
    if (threadIdx.x == 0) {
        int acc = 0;
        for (int i = 0; i < nb; i++) { int v = bsum[i]; bsum[i] = acc; acc += v; }
        rowptr[NND] = acc;
    }
}

__global__ void scanC_kernel(const int* __restrict__ cnt, const int* __restrict__ bsum,
                             int* __restrict__ rowptr, int* __restrict__ cursor)
{
    __shared__ int buf[1024];
    int t = threadIdx.x, idx = blockIdx.x * 1024 + t;
    int v = (idx < NND) ? cnt[idx] : 0;
    buf[t] = v; __syncthreads();
    for (int off = 1; off < 1024; off <<= 1) {
        int x = (t >= off) ? buf[t - off] : 0;
        __syncthreads();
        buf[t] += x;
        __syncthreads();
    }
    if (idx < NND) {
        int excl = buf[t] - v + bsum[blockIdx.x];
        rowptr[idx] = excl; cursor[idx] = excl;
    }
}

__global__ void fill_kernel(const int* __restrict__ src, const int* __restrict__ dst,
                            const float* __restrict__ ew, int* __restrict__ cursor,
                            int* __restrict__ csrs, float* __restrict__ csrw)
{
    int e = blockIdx.x * 256 + threadIdx.x;
    if (e < NED) {
        int pos = atomicAdd(&cursor[dst[e]], 1);
        csrs[pos] = src[e];
        csrw[pos] = ew[e];
    }
}

// ---------------- graph ranges via binary search on sorted graph_ids ----------------
__global__ void grstart_kernel(const int* __restrict__ gid, int* __restrict__ gr)
{
    int t = threadIdx.x;
    if (t > NGR) return;
    if (t == NGR) { gr[NGR] = NND; return; }
    int lo = 0, hi = NND;
    while (lo < hi) { int mid = (lo + hi) >> 1; if (gid[mid] < t) lo = mid + 1; else hi = mid; }
    gr[t] = lo;
}

// ---------------- K0: transpose node_feats [p][c] -> nfT [c][4+p] (padded) ---------
__global__ void transpose_kernel(const float* __restrict__ nf, float* __restrict__ nfT)
{
    __shared__ float tile[32][33];
    int tx = threadIdx.x & 31, ty = threadIdx.x >> 5;   // 32 x 8
    int p0 = blockIdx.x * 32, c0 = blockIdx.y * 32;
#pragma unroll
    for (int i = 0; i < 4; i++) {
        int p = p0 + ty + i * 8;
        if (p < NND) tile[ty + i * 8][tx] = nf[(size_t)p * 128 + c0 + tx];
    }
    __syncthreads();
#pragma unroll
    for (int i = 0; i < 4; i++) {
        int c = c0 + ty + i * 8;
        int p = p0 + tx;
        if (p < NND) nfT[(size_t)c * NSTR + 4 + p] = tile[tx][ty + i * 8];
    }
}

// zero the 4-elem guard bands of each padded column
__global__ void pad_kernel(float* __restrict__ nfT)
{
    int t = threadIdx.x;           // 1024 = 128 ch x 8 pad slots
    int c = t >> 3, i = t & 7;
    size_t off = (size_t)c * NSTR + (i < 4 ? i : (NND + i));  // 0..3 and NND+4..NND+7
    nfT[off] = 0.f;
}

// ---------------- fused conv + cross-connect(relu) + BN1 stats ----------------
template <int D>
__device__ __forceinline__ void conv_tap4(const float4& lo, const float4& mi, const float4& hi,
                                          const float* __restrict__ wl, int c,
                                          float (&acc)[4][4])
{
    float f0[4], f1[4], f2[4];
    f1[0] = mi.x; f1[1] = mi.y; f1[2] = mi.z; f1[3] = mi.w;
    if (D == 1) {
        f0[0] = lo.w; f0[1] = mi.x; f0[2] = mi.y; f0[3] = mi.z;
        f2[0] = mi.y; f2[1] = mi.z; f2[2] = mi.w; f2[3] = hi.x;
    } else if (D == 2) {
        f0[0] = lo.z; f0[1] = lo.w; f0[2] = mi.x; f0[3] = mi.y;
        f2[0] = mi.z; f2[1] = mi.w; f2[2] = hi.x; f2[3] = hi.y;
    } else {
        f0[0] = lo.y; f0[1] = lo.z; f0[2] = lo.w; f0[3] = mi.x;
        f2[0] = mi.w; f2[1] = hi.x; f2[2] = hi.y; f2[3] = hi.z;
    }
    const int BR = D - 1;
    const float4 a0 = *(const float4*)&wl[((BR * 3 + 0) * 128 + c) * 4];
    const float4 a1 = *(const float4*)&wl[((BR * 3 + 1) * 128 + c) * 4];
    const float4 a2 = *(const float4*)&wl[((BR * 3 + 2) * 128 + c) * 4];
#pragma unroll
    for (int i = 0; i < 4; i++) {
        acc[0][i] += f0[i] * a0.x + f1[i] * a1.x + f2[i] * a2.x;
        acc[1][i] += f0[i] * a0.y + f1[i] * a1.y + f2[i] * a2.y;
        acc[2][i] += f0[i] * a0.z + f1[i] * a1.z + f2[i] * a2.z;
        acc[3][i] += f0[i] * a0.w + f1[i] * a1.w + f2[i] * a2.w;
    }
}

__global__ __launch_bounds__(256)
void conv_y_stats_kernel(const float* __restrict__ nfT, const float* __restrict__ cw,
                         const float* __restrict__ cb, float* __restrict__ Y,
                         float* __restrict__ st1)
{
    __shared__ __align__(16) float wl[3 * 3 * 128 * 4];   // [br][k][c][j4] : 18 KB
    const int t  = threadIdx.x;
    const int og = blockIdx.x;   // 0..23 (4 out channels)
    for (int l = t; l < 3 * 3 * 128 * 4; l += 256) {
        int j = l & 3; int c = (l >> 2) & 127; int kb = l >> 9;  // kb = br*3+k
        int k = kb % 3, br = kb / 3;
        wl[l] = cw[(((size_t)br * 96 + og * 4 + j) * 128 + c) * 3 + k];
    }
    __syncthreads();
    const int pq = blockIdx.y * 1024 + t * 4;
    float acc[3][4][4];
#pragma unroll
    for (int br = 0; br < 3; br++)
#pragma unroll
        for (int j = 0; j < 4; j++) {
            float b = cb[br * 96 + og * 4 + j];
#pragma unroll
            for (int i = 0; i < 4; i++) acc[br][j][i] = b;
        }
    for (int c = 0; c < 128; c++) {
        const float* col = nfT + (size_t)c * NSTR + 4;
        float4 lo = *(const float4*)(col + pq - 4);
        float4 mi = *(const float4*)(col + pq);
        float4 hi = *(const float4*)(col + pq + 4);
        conv_tap4<1>(lo, mi, hi, wl, c, acc[0]);
        conv_tap4<2>(lo, mi, hi, wl, c, acc[1]);
        conv_tap4<3>(lo, mi, hi, wl, c, acc[2]);
    }
#pragma unroll
    for (int j = 0; j < 4; j++)
#pragma unroll
        for (int i = 0; i < 4; i++) {
            float a0 = acc[0][j][i], a1 = acc[1][j][i], a2 = acc[2][j][i];
            acc[0][j][i] = (a0 > 0.f ? a0 : 0.f) + a1;
            acc[1][j][i] = (a1 > 0.f ? a1 : 0.f) + a2;
            acc[2][j][i] = (a2 > 0.f ? a2 : 0.f) + a0;
        }
    bool val[4];
#pragma unroll
    for (int i = 0; i < 4; i++) val[i] = (pq + i) < NND;
    const size_t NM = (size_t)NND * 96;
#pragma unroll
    for (int br = 0; br < 3; br++)
#pragma unroll
        for (int j = 0; j < 4; j++) {
            float s = 0.f, q = 0.f;
#pragma unroll
            for (int i = 0; i < 4; i++)
                if (val[i]) { float v = acc[br][j][i]; s += v; q += v * v; }
            for (int off = 32; off; off >>= 1) {
                s += __shfl_down(s, off, 64);
                q += __shfl_down(q, off, 64);
            }
            if ((t & 63) == 0) {
                unsafeAtomicAdd(&st1[br * 96 + og * 4 + j], s);
                unsafeAtomicAdd(&st1[288 + br * 96 + og * 4 + j], q);
            }
        }
#pragma unroll
    for (int br = 0; br < 3; br++)
#pragma unroll
        for (int i = 0; i < 4; i++) {
            if (!val[i]) continue;
            float* yo = Y + (size_t)br * NM + (size_t)(pq + i) * 96 + og * 4;
            float4 v;
            v.x = acc[br][0][i]; v.y = acc[br][1][i]; v.z = acc[br][2][i]; v.w = acc[br][3][i];
            *(float4*)yo = v;
        }
}

// ---------------- BN finalize ----------------
__global__ void bn_finalize_kernel(const float* __restrict__ st, const float* __restrict__ g,
                                   const float* __restrict__ b,
                                   float* __restrict__ sc, float* __restrict__ sh,
                                   int C, int gmod)
{
    int t = threadIdx.x;
    if (t >= C) return;
    float mean = st[t] / (float)NND;
    float var  = st[C + t] / (float)NND - mean * mean;
    float rs = rsqrtf(var + EPSV);
    float gg = g[t % gmod], bb = b[t % gmod];
    float s = gg * rs;
    sc[t] = s; sh[t] = bb - mean * s;
}

// ---------------- fold BN1 affine into gcn_w: W' = diag(sc)W, b' = sh@W ----------
__global__ void fold_w_kernel(const float* __restrict__ gw, const float* __restrict__ sc1,
                              const float* __restrict__ sh1,
                              float* __restrict__ WP, float* __restrict__ BP)
{
    int t = blockIdx.x * 256 + threadIdx.x;   // 162 = 3*54 used
    if (t >= 3 * 54) return;
    int br = t / 54, o = t % 54;
    const float* W = gw + (size_t)br * 96 * 54 + o;
    float bacc = 0.f;
    for (int c = 0; c < 96; c++) {
        float w = W[c * 54];
        WP[((size_t)br * 96 + c) * 54 + o] = sc1[br * 96 + c] * w;
        bacc += sh1[br * 96 + c] * w;
    }
    BP[br * 54 + o] = bacc;
}

// ---------------- node-per-thread matmul, W staged in LDS (RELU/bias optional) ----
template <int Cin, int Cout, bool RELU>
__global__ __launch_bounds__(128)
void matmul_node_kernel(const float* __restrict__ in, const float* __restrict__ W,
                        const float* __restrict__ bias, float* __restrict__ out)
{
    constexpr int CoutP = (Cout + 3) & ~3;
    __shared__ __align__(16) float wl[Cin * CoutP];
    __shared__ float bl[CoutP];
    const int t = threadIdx.x;
    const int br = blockIdx.y;
    const float* Wb = W + (size_t)br * Cin * Cout;
    for (int l = t; l < Cin * CoutP; l += 128) {
        int c = l / CoutP, o = l % CoutP;
        wl[l] = (o < Cout) ? Wb[c * Cout + o] : 0.f;
    }
    if (t < CoutP) bl[t] = (t < Cout && bias) ? bias[br * Cout + t] : 0.f;
    __syncthreads();
    int p = blockIdx.x * 128 + t;
    if (p >= NND) return;
    float acc[CoutP];
#pragma unroll
    for (int o = 0; o < CoutP; o++) acc[o] = bl[o];
    const float* row = in + (size_t)br * NND * Cin + (size_t)p * Cin;
    if constexpr (Cin % 4 == 0) {
        const float4* row4 = (const float4*)row;
#pragma unroll
        for (int c4 = 0; c4 < Cin / 4; c4++) {
            float4 f4 = row4[c4];
            float fv[4] = {f4.x, f4.y, f4.z, f4.w};
#pragma unroll
            for (int cc = 0; cc < 4; cc++) {
                const float4* w4 = (const float4*)&wl[(c4 * 4 + cc) * CoutP];
#pragma unroll
                for (int oq = 0; oq < CoutP / 4; oq++) {
                    float4 wv = w4[oq];
                    acc[oq * 4 + 0] += fv[cc] * wv.x;
                    acc[oq * 4 + 1] += fv[cc] * wv.y;
                    acc[oq * 4 + 2] += fv[cc] * wv.z;
                    acc[oq * 4 + 3] += fv[cc] * wv.w;
                }
            }
        }
    } else if constexpr (Cin % 2 == 0) {
        const float2* row2 = (const float2*)row;
#pragma unroll
        for (int c2 = 0; c2 < Cin / 2; c2++) {
            float2 f2 = row2[c2];
            float fv[2] = {f2.x, f2.y};
#pragma unroll
            for (int cc = 0; cc < 2; cc++) {
                const float4* w4 = (const float4*)&wl[(c2 * 2 + cc) * CoutP];
#pragma unroll
                for (int oq = 0; oq < CoutP / 4; oq++) {
                    float4 wv = w4[oq];
                    acc[oq * 4 + 0] += fv[cc] * wv.x;
                    acc[oq * 4 + 1] += fv[cc] * wv.y;
                    acc[oq * 4 + 2] += fv[cc] * wv.z;
                    acc[oq * 4 + 3] += fv[cc] * wv.w;
                }
            }
        }
    } else {
#pragma unroll
        for (int c = 0; c < Cin; c++) {
            float f = row[c];
            const float4* w4 = (const float4*)&wl[c * CoutP];
#pragma unroll
            for (int oq = 0; oq < CoutP / 4; oq++) {
                float4 wv = w4[oq];
                acc[oq * 4 + 0] += f * wv.x;
                acc[oq * 4 + 1] += f * wv.y;
                acc[oq * 4 + 2] += f * wv.z;
                acc[oq * 4 + 3] += f * wv.w;
            }
        }
    }
    float* op = out + (size_t)br * NND * Cout + (size_t)p * Cout;
#pragma unroll
    for (int o = 0; o < Cout; o++) {
        float v = acc[o];
        if constexpr (RELU) v = v > 0.f ? v : 0.f;
        op[o] = v;
    }
}

// ---------------- pull 54ch x 3 branches fused, float2, + gcn_b + relu ----------
__global__ void pull3br54_kernel(const float* __restrict__ Z, const int* __restrict__ rowptr,
                                 const int* __restrict__ csrs, const float* __restrict__ csrw,
                                 const float* __restrict__ gb, float* __restrict__ H2c)
{
    int id = blockIdx.x * 256 + threadIdx.x;
    if (id >= NND * 27) return;
    int p = id / 27, q = id % 27;
    const float2* Z2 = (const float2*)Z;
    const size_t NQ = (size_t)NND * 27;
    int beg = rowptr[p], end = rowptr[p + 1];
    float a0x=0,a0y=0, a1x=0,a1y=0, a2x=0,a2y=0;
    for (int i = beg; i < end; i++) {
        float w = csrw[i];
        size_t off = (size_t)csrs[i] * 27 + q;
        float2 v0 = Z2[off];
        float2 v1 = Z2[NQ + off];
        float2 v2 = Z2[2 * NQ + off];
        a0x += w * v0.x; a0y += w * v0.y;
        a1x += w * v1.x; a1y += w * v1.y;
        a2x += w * v2.x; a2y += w * v2.y;
    }
    const float2* GB2 = (const float2*)gb;
    float2* O2 = (float2*)H2c;
    size_t ob = (size_t)p * 27 + q;
    {
        float2 b = GB2[q], r;
        r.x = a0x + b.x; r.y = a0y + b.y;
        r.x = r.x > 0.f ? r.x : 0.f; r.y = r.y > 0.f ? r.y : 0.f;
        O2[ob] = r;
    }
    {
        float2 b = GB2[27 + q], r;
        r.x = a1x + b.x; r.y = a1y + b.y;
        r.x = r.x > 0.f ? r.x : 0.f; r.y = r.y > 0.f ? r.y : 0.f;
        O2[NQ + ob] = r;
    }
    {
        float2 b = GB2[54 + q], r;
        r.x = a2x + b.x; r.y = a2y + b.y;
        r.x = r.x > 0.f ? r.x : 0.f; r.y = r.y > 0.f ? r.y : 0.f;
        O2[2 * NQ + ob] = r;
    }
}

// ---------------- pull + bias + relu, float2 (C even) ----------------
template <int C>
__global__ void pull_br2_kernel(const float* __restrict__ in, const int* __restrict__ rowptr,
                                const int* __restrict__ csrs, const float* __restrict__ csrw,
                                const float* __restrict__ bias, float* __restrict__ out)
{
    constexpr int C2 = C / 2;
    int id = blockIdx.x * 256 + threadIdx.x;
    if (id >= NND * C2) return;
    int p = id / C2, q = id % C2;
    const float2* in2 = (const float2*)in;
    int beg = rowptr[p], end = rowptr[p + 1];
    float ax = 0.f, ay = 0.f;
    for (int i = beg; i < end; i++) {
        float w = csrw[i];
        float2 v = in2[(size_t)csrs[i] * C2 + q];
        ax += w * v.x; ay += w * v.y;
    }
    float2 b = ((const float2*)bias)[q];
    float2 r;
    r.x = ax + b.x; r.y = ay + b.y;
    r.x = r.x > 0.f ? r.x : 0.f; r.y = r.y > 0.f ? r.y : 0.f;
    ((float2*)out)[(size_t)p * C2 + q] = r;
}

// ---------------- pull + bias + relu, scalar (odd C) ----------------
template <int C>
__global__ void pull_br1_kernel(const float* __restrict__ in, const int* __restrict__ rowptr,
                                const int* __restrict__ csrs, const float* __restrict__ csrw,
                                const float* __restrict__ bias, float* __restrict__ out)
{
    int id = blockIdx.x * 256 + threadIdx.x;
    if (id >= NND * C) return;
    int p = id / C, c = id % C;
    int beg = rowptr[p], end = rowptr[p + 1];
    float acc = 0.f;
    for (int i = beg; i < end; i++)
        acc += csrw[i] * in[(size_t)csrs[i] * C + c];
    float v = acc + bias[c];
    out[id] = v > 0.f ? v : 0.f;
}

// ---------------- pull + bias + relu, float4 (C % 4 == 0) ----------------
template <int C>
__global__ void pull_br4_kernel(const float* __restrict__ in, const int* __restrict__ rowptr,
                                const int* __restrict__ csrs, const float* __restrict__ csrw,
                                const float* __restrict__ bias, float* __restrict__ out)
{
    constexpr int C4 = C / 4;
    int id = blockIdx.x * 256 + threadIdx.x;
    if (id >= NND * C4) return;
    int p = id / C4, q = id % C4;
    const float4* in4 = (const float4*)in;
    int beg = rowptr[p], end = rowptr[p + 1];
    float ax = 0.f, ay = 0.f, az = 0.f, aw = 0.f;
    for (int i = beg; i < end; i++) {
        float w = csrw[i];
        float4 v = in4[(size_t)csrs[i] * C4 + q];
        ax += w * v.x; ay += w * v.y; az += w * v.z; aw += w * v.w;
    }
    float4 b = ((const float4*)bias)[q];
    float4 r;
    r.x = ax + b.x; r.y = ay + b.y; r.z = az + b.z; r.w = aw + b.w;
    r.x = r.x > 0.f ? r.x : 0.f; r.y = r.y > 0.f ? r.y : 0.f;
    r.z = r.z > 0.f ? r.z : 0.f; r.w = r.w > 0.f ? r.w : 0.f;
    ((float4*)out)[(size_t)p * C4 + q] = r;
}

// ---------------- K6: press conv (3ch,K=3,SAME over 54) + BN2 stats ----------------
__global__ void press_stats_kernel(const float* __restrict__ H2, const float* __restrict__ pw,
                                   const float* __restrict__ pb, float* __restrict__ PRS,
                                   float* __restrict__ st2)
{
    __shared__ float ls[54], lq[54];
    int t = threadIdx.x;
    if (t < 54) { ls[t] = 0.f; lq[t] = 0.f; }
    __syncthreads();
    float pwf[9];
#pragma unroll
    for (int q = 0; q < 9; q++) pwf[q] = pw[q];
    float pbf = pb[0];
    const size_t NM = (size_t)NND * 54;
    size_t base = (size_t)blockIdx.x * 6912;
    for (int q = 0; q < 27; q++) {
        size_t idx = base + q * 256 + t;
        if (idx < NM) {
            int p = (int)(idx / 54), h = (int)(idx % 54);
            float sum = pbf;
#pragma unroll
            for (int i = 0; i < 3; i++)
#pragma unroll
                for (int k = 0; k < 3; k++) {
                    int hh = h + k - 1;
                    if (hh >= 0 && hh < 54)
                        sum += pwf[i * 3 + k] * H2[(size_t)i * NM + (size_t)p * 54 + hh];
                }
            PRS[idx] = sum;
            atomicAdd(&ls[h], sum); atomicAdd(&lq[h], sum * sum);
        }
    }
    __syncthreads();
    if (t < 54) {
        unsafeAtomicAdd(&st2[t], ls[t]);
        unsafeAtomicAdd(&st2[54 + t], lq[t]);
    }
}

// ---------------- K8: emd = affine(pressed) ----------------
__global__ void emd_kernel(float* __restrict__ PRS, const float* __restrict__ sc2,
                           const float* __restrict__ sh2, float* __restrict__ outp)
{
    int id = blockIdx.x * 256 + threadIdx.x;
    if (id >= NND * 54) return;
    int h = id % 54;
    float v = PRS[id] * sc2[h] + sh2[h];
    PRS[id] = v;
    outp[id] = v;
}

// ---------------- K15: graph pooling, block per graph, no atomics ----------------
__global__ void pool_kernel(const float* __restrict__ H1, const float* __restrict__ H2j,
                            const float* __restrict__ H3, const int* __restrict__ gr,
                            float* __restrict__ HG)
{
    __shared__ float part[4][75];
    int t = threadIdx.x;   // 300 = 75 x 4
    int c = t % 75, sub = t / 75;
    int g = blockIdx.x;
    int s = gr[g], e = gr[g + 1];
    float acc = 0.f;
    for (int p = s + sub; p < e; p += 4) {
        float v;
        if (c < 34)      v = H1[(size_t)p * 34 + c];
        else if (c < 59) v = H2j[(size_t)p * 25 + (c - 34)];
        else             v = H3[(size_t)p * 16 + (c - 59)];
        acc += v;
    }
    part[sub][c] = acc;
    __syncthreads();
    if (t < 75) HG[g * 75 + t] = part[0][t] + part[1][t] + part[2][t] + part[3][t];
}

// ---------------- K16: BN3 + cls matmuls, single block ----------------
__global__ void final_kernel(const float* __restrict__ HG, const float* __restrict__ g3,
                             const float* __restrict__ b3,
                             const float* __restrict__ w1, const float* __restrict__ b1,
                             const float* __restrict__ w2, const float* __restrict__ b2,
                             float* __restrict__ outp)
{
    __shared__ float hg[64 * 75];
    __shared__ float o1[64 * 120];
    __shared__ float sc[75], sh[75];
    int t = threadIdx.x;   // 512
    for (int idx = t; idx < 64 * 75; idx += 512) hg[idx] = HG[idx];
    __syncthreads();
    if (t < 75) {
        float s = 0.f, q = 0.f;
        for (int r = 0; r < 64; r++) { float v = hg[r * 75 + t]; s += v; q += v * v; }
        float m = s / 64.f, var = q / 64.f - m * m;
        float rs = rsqrtf(var + EPSV);
        float scale = g3[t] * rs;
        sc[t] = scale; sh[t] = b3[t] - m * scale;
    }
    __syncthreads();
    for (int idx = t; idx < 64 * 75; idx += 512) { int c = idx % 75; hg[idx] = hg[idx] * sc[c] + sh[c]; }
    __syncthreads();
    for (int idx = t; idx < 64 * 120; idx += 512) {
        int r = idx / 120, o = idx % 120;
        float a = b1[o];
        for (int c = 0; c < 75; c++) a += hg[r * 75 + c] * w1[c * 120 + o];
        o1[idx] = a;
    }
    __syncthreads();
    for (int idx = t; idx < 640; idx += 512) {
        int r = idx / 10, o = idx % 10;
        float a = b2[o];
        for (int k = 0; k < 120; k++) a += o1[r * 120 + k] * w2[k * 10 + o];
        outp[idx] = a;
    }
}

extern "C" void kernel_launch(void* const* d_in, const int* in_sizes, int n_in,
                              void* d_out, int out_size, void* d_ws, size_t ws_size,
                              hipStream_t stream)
{
    (void)in_sizes; (void)n_in; (void)out_size;
    const float* nf     = (const float*)d_in[0];
    const float* ew     = (const float*)d_in[1];
    const float* conv_w = (const float*)d_in[2];
    const float* conv_b = (const float*)d_in[3];
    const float* gcn_w  = (const float*)d_in[4];
    const float* gcn_b  = (const float*)d_in[5];
    const float* bn1_g = (const float*)d_in[6],  *bn1_b = (const float*)d_in[7];
    const float* bn2_g = (const float*)d_in[8],  *bn2_b = (const float*)d_in[9];
    const float* bn3_g = (const float*)d_in[10], *bn3_b = (const float*)d_in[11];
    const float* press_w = (const float*)d_in[12], *press_b = (const float*)d_in[13];
    const float* jk_w1 = (const float*)d_in[14], *jk_b1 = (const float*)d_in[15];
    const float* jk_w2 = (const float*)d_in[16], *jk_b2 = (const float*)d_in[17];
    const float* jk_w3 = (const float*)d_in[18], *jk_b3 = (const float*)d_in[19];
    const float* cls1_w = (const float*)d_in[20], *cls1_b = (const float*)d_in[21];
    const float* cls2_w = (const float*)d_in[22], *cls2_b = (const float*)d_in[23];
    const int* esrc = (const int*)d_in[24];
    const int* edst = (const int*)d_in[25];
    const int* gid  = (const int*)d_in[26];
    float* out = (float*)d_out;   // fp32 outputs: (logits[640], emd[2.7M])

    float* ws = (float*)d_ws;
    const size_t NM = (size_t)NND * 96;
    const size_t N54 = (size_t)NND * 54;
    float* X   = ws;                 // 3*NM   (nfT during conv; Z after)
    float* Y   = X + 3 * NM;         // 3*NM   (jk buffers later)
    float* H2c = Y + 3 * NM;         // 3*N54
    float* PRS = H2c + 3 * N54;      // N54
    float* ST1 = PRS + N54;          // 576
    float* SC1 = ST1 + 576;          // 288
    float* SH1 = SC1 + 288;          // 288
    float* ST2 = SH1 + 288;          // 108
    float* SC2 = ST2 + 108;          // 54
    float* SH2 = SC2 + 54;           // 54
    float* HG  = SH2 + 54;           // 4800
    // CSR-by-dst + pooling + folded-W scratch
    int* CNT    = (int*)(HG + 4800);     // 50000
    int* ROWPTR = CNT + NND;             // 50001
    int* CURSOR = ROWPTR + NND + 1;      // 50000
    int* CSRS   = CURSOR + NND;          // 800000
    float* CSRW = (float*)(CSRS + NED);  // 800000
    int* BSUM   = (int*)(CSRW + NED);    // 64 (49 used)
    int* GR     = BSUM + 64;             // 65 (+pad 3)
    float* WP   = (float*)(GR + 68);     // 3*96*54 = 15552 (BN1-folded gcn_w)
    float* BP   = WP + 15552;            // 3*54 = 162
    size_t need = (size_t)((BP + 162) - ws) * sizeof(float);
    if (ws_size < need) return;      // ws too small -> fail loudly in validation

    // aliases
    float* nfT  = X;                 // [128][NSTR] padded — dead once conv_y done
    float* Z    = X;                 // [3][N][54] — BN1-affine(Y) @ W'
    float* P1   = Y;                           // N*34 (Y dead after Z computed)
    float* H1j  = P1 + (size_t)NND * 34;       // N*34
    float* P2   = H1j + (size_t)NND * 34;      // N*25
    float* H2j  = P2 + (size_t)NND * 25;       // N*25
    float* P3   = H2j + (size_t)NND * 25;      // N*16
    float* H3j  = P3 + (size_t)NND * 16;       // N*16

    // zero stats (ST1..SH2 = 1368 floats) and CSR histogram
    hipMemsetAsync(ST1, 0, 1368 * sizeof(float), stream);
    hipMemsetAsync(CNT, 0, NND * sizeof(int), stream);

    // CSR build (multi-block scan) + graph ranges
    hist_kernel<<<(NED + 255) / 256, 256, 0, stream>>>(edst, CNT);
    scanA_kernel<<<49, 256, 0, stream>>>(CNT, BSUM);
    scanB_kernel<<<1, 64, 0, stream>>>(BSUM, ROWPTR, 49);
    scanC_kernel<<<49, 1024, 0, stream>>>(CNT, BSUM, ROWPTR, CURSOR);
    fill_kernel<<<(NED + 255) / 256, 256, 0, stream>>>(esrc, edst, ew, CURSOR, CSRS, CSRW);
    grstart_kernel<<<1, 128, 0, stream>>>(gid, GR);

    // K0: transpose node feats into padded [c][4+p] (X region) + zero guard bands
    transpose_kernel<<<dim3((NND + 31) / 32, 4), 256, 0, stream>>>(nf, nfT);
    pad_kernel<<<1, 1024, 0, stream>>>(nfT);

    // K1+K2: fused dilated convs + cross-connect + BN1 stats
    conv_y_stats_kernel<<<dim3(24, 49), 256, 0, stream>>>(nfT, conv_w, conv_b, Y, ST1);
    bn_finalize_kernel<<<1, 512, 0, stream>>>(ST1, bn1_g, bn1_b, SC1, SH1, 288, 96);

    // fold BN1 into gcn_w; Z = Y @ W' + b'  (pre-aggregation matmul, 96->54)
    fold_w_kernel<<<1, 256, 0, stream>>>(gcn_w, SC1, SH1, WP, BP);
    matmul_node_kernel<96, 54, false><<<dim3((NND + 127) / 128, 3), 128, 0, stream>>>(
        Y, WP, BP, Z);

    // pull 54ch x 3 branches + gcn_b + relu -> H2c
    pull3br54_kernel<<<(NND * 27 + 255) / 256, 256, 0, stream>>>(
        Z, ROWPTR, CSRS, CSRW, gcn_b, H2c);

    // K6/K7/K8: press + BN2 + emd out (fp32 at element offset 640)
    press_stats_kernel<<<(int)((N54 + 6911) / 6912), 256, 0, stream>>>(H2c, press_w, press_b, PRS, ST2);
    bn_finalize_kernel<<<1, 512, 0, stream>>>(ST2, bn2_g, bn2_b, SC2, SH2, 54, 54);
    emd_kernel<<<(int)((N54 + 255) / 256), 256, 0, stream>>>(PRS, SC2, SH2, out + 640);

    // JK layer 1: matmul first (54->34, no bias), gather 34ch + b1 + relu
    matmul_node_kernel<54, 34, false><<<dim3((NND + 127) / 128, 1), 128, 0, stream>>>(
        PRS, jk_w1, nullptr, P1);
    pull_br2_kernel<34><<<(NND * 17 + 255) / 256, 256, 0, stream>>>(
        P1, ROWPTR, CSRS, CSRW, jk_b1, H1j);

    // JK layer 2: matmul first (34->25), gather 25ch + b2 + relu
    matmul_node_kernel<34, 25, false><<<dim3((NND + 127) / 128, 1), 128, 0, stream>>>(
        H1j, jk_w2, nullptr, P2);
    pull_br1_kernel<25><<<(NND * 25 + 255) / 256, 256, 0, stream>>>(
        P2, ROWPTR, CSRS, CSRW, jk_b2, H2j);

    // JK layer 3: matmul first (25->16), gather 16ch + b3 + relu
    matmul_node_kernel<25, 16, false><<<dim3((NND + 127) / 128, 1), 128, 0, stream>>>(
        H2j, jk_w3, nullptr, P3);
    pull_br4_kernel<16><<<(NND * 4 + 255) / 256, 256, 0, stream>>>(
        P3, ROWPTR, CSRS, CSRW, jk_b3, H3j);

    // pooling (block per graph, no atomics) + final
    pool_kernel<<<NGR, 300, 0, stream>>>(H1j, H2j, H3j, GR, HG);
    final_kernel<<<1, 512, 0, stream>>>(HG, bn3_g, bn3_b, cls1_w, cls1_b, cls2_w, cls2_b, out);
}